// Round 6
// baseline (54.482 us; speedup 1.0000x reference)
//
#include <hip/hip_runtime.h>
#include <hip/hip_bf16.h>

typedef __attribute__((ext_vector_type(8))) __bf16 bf16x8;
typedef __attribute__((ext_vector_type(4))) float f32x4;

#define B_   64
#define L_   512
#define HID_ 768
#define M_   128
#define R_   64
#define P_   8

// XOR-swizzle for row-major LDS tiles (ushort-index units, 8-elem aligned k).
__device__ __forceinline__ int swz(int row, int k, int stride) {
    return row * stride + (k ^ ((row & 7) << 3));
}

// async 16B global -> LDS (linear dest: wave-uniform base + lane*16)
#define GLL16(gp, lp)                                                        \
    __builtin_amdgcn_global_load_lds(                                        \
        (const __attribute__((address_space(1))) void*)(gp),                 \
        (__attribute__((address_space(3))) void*)(lp), 16, 0, 0)

__device__ __forceinline__ bf16x8 cvt8(float4 f0, float4 f1) {
    bf16x8 v;
    v[0]=(__bf16)f0.x; v[1]=(__bf16)f0.y; v[2]=(__bf16)f0.z; v[3]=(__bf16)f0.w;
    v[4]=(__bf16)f1.x; v[5]=(__bf16)f1.y; v[6]=(__bf16)f1.z; v[7]=(__bf16)f1.w;
    return v;
}

// ---- Kw: transpose+cast proj_W -> Wt, PRE-SWIZZLED per 64-k chunk --------
// Wt[c*8192 + n*64 + (kk ^ ((n&7)<<3))] = W[(c*64+kk)*128 + n]
__global__ __launch_bounds__(256) void k_wt(const float* __restrict__ W,
                                            __bf16* __restrict__ Wt) {
    int idx = blockIdx.x * 256 + threadIdx.x;   // k*128 + n  (coalesced read)
    int k = idx >> 7, n = idx & 127;
    int c = k >> 6, kk = k & 63;
    Wt[c * 8192 + n * 64 + (kk ^ ((n & 7) << 3))] = (__bf16)W[idx];
}

// ---- K_main: fused proj(128 tokens -> LDS) + probes + maxsim partials ----
// Grid dim3(B_, 4): block (b, c) -> XCD b%8 (64%8==0 so c doesn't change XCD).
// 1024 threads = 16 waves = 8 row-groups(16 tok) x 2 col-groups(64 dims).
__global__ __launch_bounds__(1024, 4) void k_main(
        const float* __restrict__ hidden, const __bf16* __restrict__ Wt,
        const float* __restrict__ lp, const float* __restrict__ sW,
        const float* __restrict__ oW, const float* __restrict__ dW,
        const int* __restrict__ st, const int* __restrict__ ot,
        const int* __restrict__ sf, const int* __restrict__ ctx,
        const int* __restrict__ btw, float* __restrict__ pm) {
    __shared__ __align__(16) __bf16 Al[2][128 * 64];    // 2 x 16 KB (tokens x k)
    __shared__ __align__(16) __bf16 Bl[2][128 * 64];    // 2 x 16 KB (dims x k)
    __shared__ __align__(16) __bf16 Dl[128 * 128];      // 32 KB (tokens x dims)
    __shared__ float nbuf[2][128];
    __shared__ float evl[128];
    __shared__ int anyf;

    const int t = threadIdx.x;
    const int lane = t & 63, w = t >> 6;
    const int rlo = lane & 15, g = lane >> 4;
    const int b = blockIdx.x, c = blockIdx.y;
    const int rg = w & 7, cg = w >> 3;
    const int row0 = b * 512 + c * 128;

    // ---- evidence: any(between) over FULL row, then this chunk's mask ----
    if (t == 0) anyf = 0;
    __syncthreads();
    if (t < 512) { if (btw[b * L_ + t]) anyf = 1; }   // benign race: store 1
    __syncthreads();
    const int any = anyf;
    if (t < 128) {
        int j = c * 128 + t;
        evl[t] = ((any ? btw[b * L_ + j] : ctx[b * L_ + j]) != 0) ? 1.0f : 0.0f;
    }

    // ---- phase 1 staging geometry ----
    const int ar = t >> 3;            // token row 0..127 (8 threads/row)
    const int ac = (t & 7) * 8;       // k offset, step 8
    const float* arow = hidden + (size_t)(row0 + ar) * HID_ + ac;

    f32x4 acc[4] = {};                // [ct] : 16 tok x 64 dims per wave

    // prologue: stage chunk 0 into buffer 0
    GLL16(Wt + w * 512 + lane * 8, &Bl[0][w * 512]);
    {
        float4 f0 = ((const float4*)arow)[0];
        float4 f1 = ((const float4*)arow)[1];
        *(bf16x8*)&Al[0][swz(ar, ac, 64)] = cvt8(f0, f1);
    }

    // ---- probe build overlaps prologue DMA latency ----
    const int sb = st[b], ob = ot[b], db = sf[b];
    const float* sv = sW + sb * M_;
    const float* ov = oW + ob * M_;
    const float* dv = dW + db * M_;
    bf16x8 qF[2][4];                  // [pt2][ks] : 32 probes per wave
#pragma unroll
    for (int pt2 = 0; pt2 < 2; ++pt2) {
        const float* lpp = lp + (size_t)(w * 32 + pt2 * 16 + rlo) * M_;
        float qv[32];
        float ssq = 0.f;
#pragma unroll
        for (int ks = 0; ks < 4; ++ks) {
#pragma unroll
            for (int h = 0; h < 2; ++h) {
                const int m0 = ks * 32 + g * 8 + h * 4;
                float4 a  = *(const float4*)(lpp + m0);
                float4 s4 = *(const float4*)(sv + m0);
                float4 o4 = *(const float4*)(ov + m0);
                float4 d4 = *(const float4*)(dv + m0);
                float x0 = a.x + s4.x + o4.x + d4.x;
                float x1 = a.y + s4.y + o4.y + d4.y;
                float x2 = a.z + s4.z + o4.z + d4.z;
                float x3 = a.w + s4.w + o4.w + d4.w;
                qv[ks * 8 + h * 4 + 0] = x0;
                qv[ks * 8 + h * 4 + 1] = x1;
                qv[ks * 8 + h * 4 + 2] = x2;
                qv[ks * 8 + h * 4 + 3] = x3;
                ssq += x0 * x0 + x1 * x1 + x2 * x2 + x3 * x3;
            }
        }
        ssq += __shfl_xor(ssq, 16);
        ssq += __shfl_xor(ssq, 32);
        const float scq = 1.0f / fmaxf(sqrtf(ssq), 1e-12f);
#pragma unroll
        for (int ks = 0; ks < 4; ++ks)
#pragma unroll
            for (int j = 0; j < 8; ++j)
                qF[pt2][ks][j] = (__bf16)(qv[ks * 8 + j] * scq);
    }
    __syncthreads();   // chunk-0 staging complete

    // ---- phase 1: GEMM over 12 k-chunks, 2-phase pipeline ----
    for (int ci = 0; ci < 12; ++ci) {
        const int cur = ci & 1;
        const bool pre = ci < 11;
        float4 f0, f1;
        if (pre) {   // issue next-chunk loads BEFORE compute
            GLL16(Wt + (ci + 1) * 8192 + w * 512 + lane * 8, &Bl[cur ^ 1][w * 512]);
            const float* src = arow + (ci + 1) * 64;
            f0 = ((const float4*)src)[0];
            f1 = ((const float4*)src)[1];
        }
#pragma unroll
        for (int s = 0; s < 2; ++s) {
            const int kk = s * 32 + g * 8;
            bf16x8 aF = *(const bf16x8*)&Al[cur][swz(rg * 16 + rlo, kk, 64)];
#pragma unroll
            for (int ct = 0; ct < 4; ++ct) {
                bf16x8 bF = *(const bf16x8*)&Bl[cur][swz(cg * 64 + ct * 16 + rlo, kk, 64)];
                acc[ct] = __builtin_amdgcn_mfma_f32_16x16x32_bf16(aF, bF, acc[ct], 0, 0, 0);
            }
        }
        if (pre) {   // write-late: cvt + ds_write after compute
            *(bf16x8*)&Al[cur ^ 1][swz(ar, ac, 64)] = cvt8(f0, f1);
        }
        __syncthreads();
    }

    // ---- norm across the two col-groups, write D chunk to LDS ----
    float ss[4];
#pragma unroll
    for (int r = 0; r < 4; ++r)
        ss[r] = acc[0][r] * acc[0][r] + acc[1][r] * acc[1][r]
              + acc[2][r] * acc[2][r] + acc[3][r] * acc[3][r];
#pragma unroll
    for (int r = 0; r < 4; ++r)
#pragma unroll
        for (int off = 1; off < 16; off <<= 1) ss[r] += __shfl_xor(ss[r], off);
    if (rlo == 0) {
#pragma unroll
        for (int r = 0; r < 4; ++r) nbuf[cg][rg * 16 + g * 4 + r] = ss[r];
    }
    __syncthreads();
    float sc[4];
#pragma unroll
    for (int r = 0; r < 4; ++r) {
        const int row = rg * 16 + g * 4 + r;
        sc[r] = 1.0f / fmaxf(sqrtf(nbuf[0][row] + nbuf[1][row]), 1e-12f);
    }
#pragma unroll
    for (int ct = 0; ct < 4; ++ct)
#pragma unroll
        for (int r = 0; r < 4; ++r) {
            const int row = rg * 16 + g * 4 + r;
            const int col = cg * 64 + ct * 16 + rlo;
            Dl[row * 128 + (col ^ ((row & 7) << 3))] = (__bf16)(acc[ct][r] * sc[r]);
        }
    __syncthreads();

    // ---- phase 2: 512 probes vs 128 tokens, masked max ----
    float vmax[2][4];
#pragma unroll
    for (int pt2 = 0; pt2 < 2; ++pt2)
#pragma unroll
        for (int r = 0; r < 4; ++r) vmax[pt2][r] = -1e30f;

#pragma unroll
    for (int tt = 0; tt < 8; ++tt) {
        f32x4 pacc[2] = {};
#pragma unroll
        for (int ks = 0; ks < 4; ++ks) {
            bf16x8 bF = *(const bf16x8*)&Dl[swz(tt * 16 + rlo, ks * 32 + g * 8, 128)];
            pacc[0] = __builtin_amdgcn_mfma_f32_16x16x32_bf16(qF[0][ks], bF, pacc[0], 0, 0, 0);
            pacc[1] = __builtin_amdgcn_mfma_f32_16x16x32_bf16(qF[1][ks], bF, pacc[1], 0, 0, 0);
        }
        const float e = evl[tt * 16 + rlo];
#pragma unroll
        for (int pt2 = 0; pt2 < 2; ++pt2)
#pragma unroll
            for (int r = 0; r < 4; ++r) {
                float sv2 = (e > 0.5f) ? pacc[pt2][r] : -1e4f;
                vmax[pt2][r] = fmaxf(vmax[pt2][r], sv2);
            }
    }

    // reduce over the 16 token-columns (lanes rlo 0..15)
#pragma unroll
    for (int pt2 = 0; pt2 < 2; ++pt2)
#pragma unroll
        for (int r = 0; r < 4; ++r)
#pragma unroll
            for (int off = 1; off < 16; off <<= 1)
                vmax[pt2][r] = fmaxf(vmax[pt2][r], __shfl_xor(vmax[pt2][r], off));

    if (rlo == 0) {
        float* dst = pm + (size_t)(b * 4 + c) * 512 + w * 32;
#pragma unroll
        for (int pt2 = 0; pt2 < 2; ++pt2)
#pragma unroll
            for (int r = 0; r < 4; ++r)
                dst[pt2 * 16 + g * 4 + r] = vmax[pt2][r];
    }
}

// ---- K_reduce: max over 4 chunks, threshold, sum over P=8 -> logits ------
__global__ __launch_bounds__(512) void k_reduce(const float* __restrict__ pm,
                                                float* __restrict__ out) {
    const int b = blockIdx.x, t = threadIdx.x;
    float m = -1e30f;
#pragma unroll
    for (int c = 0; c < 4; ++c)
        m = fmaxf(m, pm[(size_t)(b * 4 + c) * 512 + t]);
    m = (m > -1000.0f) ? m : 0.0f;
    m += __shfl_xor(m, 1);
    m += __shfl_xor(m, 2);
    m += __shfl_xor(m, 4);
    if ((t & 7) == 0) out[b * R_ + (t >> 3)] = m;
}

// ---------------- launcher ----------------
extern "C" void kernel_launch(void* const* d_in, const int* in_sizes, int n_in,
                              void* d_out, int out_size, void* d_ws, size_t ws_size,
                              hipStream_t stream) {
    const float* hidden = (const float*)d_in[0];
    const int*   ctx    = (const int*)d_in[1];
    const int*   btw    = (const int*)d_in[2];
    const int*   st     = (const int*)d_in[3];
    const int*   ot     = (const int*)d_in[4];
    const int*   sf     = (const int*)d_in[5];
    const float* W      = (const float*)d_in[6];
    const float* lp     = (const float*)d_in[7];
    const float* sW     = (const float*)d_in[8];
    const float* oW     = (const float*)d_in[9];
    const float* dW     = (const float*)d_in[10];
    float* out = (float*)d_out;

    char* ws = (char*)d_ws;
    __bf16* Wt = (__bf16*)ws;                       // 196608 B (pre-swizzled)
    float*  pm = (float*)(ws + 196608);             // 524288 B

    k_wt    <<<(HID_ * M_) / 256, 256, 0, stream>>>(W, Wt);
    k_main  <<<dim3(B_, 4), 1024, 0, stream>>>(hidden, Wt, lp, sW, oW, dW,
                                               st, ot, sf, ctx, btw, pm);
    k_reduce<<<B_, 512, 0, stream>>>(pm, out);
}

// Round 7
// 44.076 us; speedup vs baseline: 1.2361x; 1.2361x over previous
//
#include <hip/hip_runtime.h>
#include <hip/hip_bf16.h>

typedef __attribute__((ext_vector_type(8))) __bf16 bf16x8;
typedef __attribute__((ext_vector_type(4))) float f32x4;

#define B_   64
#define L_   512
#define HID_ 768
#define M_   128
#define R_   64
#define P_   8

// 3-bit XOR swizzle for 64-wide LDS tiles (ushort units, 8-aligned k).
__device__ __forceinline__ int swz(int row, int k, int stride) {
    return row * stride + (k ^ ((row & 7) << 3));
}
// 4-bit XOR swizzle for 128-wide tiles: spreads rows 4 AND 8 apart -> no
// 8-way write conflicts in the repack epilogue (R6 counter: 524288 conflicts).
__device__ __forceinline__ int swz4(int row, int k) {
    return row * 128 + (k ^ ((row & 15) << 3));
}

// async 16B global -> LDS (linear dest: wave-uniform base + lane*16)
#define GLL16(gp, lp)                                                        \
    __builtin_amdgcn_global_load_lds(                                        \
        (const __attribute__((address_space(1))) void*)(gp),                 \
        (__attribute__((address_space(3))) void*)(lp), 16, 0, 0)

__device__ __forceinline__ bf16x8 cvt8(float4 f0, float4 f1) {
    bf16x8 v;
    v[0]=(__bf16)f0.x; v[1]=(__bf16)f0.y; v[2]=(__bf16)f0.z; v[3]=(__bf16)f0.w;
    v[4]=(__bf16)f1.x; v[5]=(__bf16)f1.y; v[6]=(__bf16)f1.z; v[7]=(__bf16)f1.w;
    return v;
}

// ---- Kw: transpose+cast proj_W -> Wt, PRE-SWIZZLED per 64-k chunk --------
__global__ __launch_bounds__(256) void k_wt(const float* __restrict__ W,
                                            __bf16* __restrict__ Wt) {
    int idx = blockIdx.x * 256 + threadIdx.x;   // k*128 + n  (coalesced read)
    int k = idx >> 7, n = idx & 127;
    int c = k >> 6, kk = k & 63;
    Wt[c * 8192 + n * 64 + (kk ^ ((n & 7) << 3))] = (__bf16)W[idx];
}

// ---- K2: D = l2norm(hidden @ W), bf16 MFMA, 2-phase pipeline -------------
// 512 threads: 8 waves = 4 row-blocks x 2 col-halves. Grid dim3(B_, 8).
// Stores D PRE-SWIZZLED (4-bit): D[row*128 + (col ^ ((row&15)<<3))]
__global__ __launch_bounds__(512, 4) void k_proj(const float* __restrict__ hidden,
                                                 const __bf16* __restrict__ Wt,
                                                 __bf16* __restrict__ D) {
    __shared__ __align__(16) __bf16 Al[2][64 * 64];     // 2 x 8 KB
    __shared__ __align__(16) __bf16 Bl[2][128 * 64];    // 2 x 16 KB
    __shared__ float nbuf[2][64];
    const int t = threadIdx.x;
    const int lane = t & 63, w = t >> 6;
    const int rlo = lane & 15, g = lane >> 4;
    const int rb = w & 3, ch = w >> 2;      // row-block 0..3, col-half 0..1
    const int row0 = blockIdx.x * 512 + blockIdx.y * 64;   // b*512 + j*64

    f32x4 acc[4] = {};

    const int ar = t >> 3;            // A stage: row 0..63 (8 threads/row)
    const int ac = (t & 7) * 8;       //          k offset, step 8
    const float* arow = hidden + (size_t)(row0 + ar) * HID_ + ac;

    // ---- prologue: stage chunk 0 into buffer 0 ----
    GLL16(Wt + w * 1024 + lane * 8,       &Bl[0][w * 1024]);
    GLL16(Wt + w * 1024 + 512 + lane * 8, &Bl[0][w * 1024 + 512]);
    {
        float4 f0 = *(const float4*)(arow);
        float4 f1 = *(const float4*)(arow + 4);
        *(bf16x8*)&Al[0][swz(ar, ac, 64)] = cvt8(f0, f1);
    }
    __syncthreads();

    for (int ci = 0; ci < 12; ++ci) {
        const int cur = ci & 1;
        const bool pre = ci < 11;
        float4 f0, f1;
        if (pre) {   // issue next-chunk loads BEFORE compute
            const __bf16* wsrc = Wt + (ci + 1) * 8192 + w * 1024;
            GLL16(wsrc + lane * 8,       &Bl[cur ^ 1][w * 1024]);
            GLL16(wsrc + 512 + lane * 8, &Bl[cur ^ 1][w * 1024 + 512]);
            const float* src = arow + (ci + 1) * 64;
            f0 = *(const float4*)(src);
            f1 = *(const float4*)(src + 4);
        }
#pragma unroll
        for (int s = 0; s < 2; ++s) {
            int kk = s * 32 + g * 8;
            bf16x8 aF = *(const bf16x8*)&Al[cur][swz(rb * 16 + rlo, kk, 64)];
#pragma unroll
            for (int c = 0; c < 4; ++c) {
                bf16x8 bF = *(const bf16x8*)&Bl[cur][swz(ch * 64 + c * 16 + rlo, kk, 64)];
                acc[c] = __builtin_amdgcn_mfma_f32_16x16x32_bf16(aF, bF, acc[c], 0, 0, 0);
            }
        }
        if (pre) {   // write-late: cvt + ds_write after compute
            *(bf16x8*)&Al[cur ^ 1][swz(ar, ac, 64)] = cvt8(f0, f1);
        }
        __syncthreads();
    }

    // ---- norm: partial over this wave's 64 cols, exchange across halves ----
    float ss[4] = {0.f, 0.f, 0.f, 0.f};
#pragma unroll
    for (int c = 0; c < 4; ++c)
#pragma unroll
        for (int r = 0; r < 4; ++r) ss[r] += acc[c][r] * acc[c][r];
#pragma unroll
    for (int r = 0; r < 4; ++r)
#pragma unroll
        for (int off = 1; off < 16; off <<= 1) ss[r] += __shfl_xor(ss[r], off);
    if (rlo == 0) {
#pragma unroll
        for (int r = 0; r < 4; ++r) nbuf[ch][rb * 16 + g * 4 + r] = ss[r];
    }
    __syncthreads();
    float sc[4];
#pragma unroll
    for (int r = 0; r < 4; ++r) {
        float tot = nbuf[0][rb * 16 + g * 4 + r] + nbuf[1][rb * 16 + g * 4 + r];
        sc[r] = 1.0f / fmaxf(sqrtf(tot), 1e-12f);
    }

    // ---- repack into LDS (4-bit pre-swizzle), then coalesced vector store ----
    __bf16* Dst = (__bf16*)Al;     // 16 KB, free after last chunk barrier
#pragma unroll
    for (int c = 0; c < 4; ++c)
#pragma unroll
        for (int r = 0; r < 4; ++r) {
            int row = rb * 16 + g * 4 + r;
            int col = ch * 64 + c * 16 + rlo;
            Dst[swz4(row, col)] = (__bf16)(acc[c][r] * sc[r]);
        }
    __syncthreads();
#pragma unroll
    for (int h = 0; h < 2; ++h) {
        int row = (t >> 4) + h * 32;
        int seg = t & 15;
        bf16x8 v = *(const bf16x8*)&Dst[row * 128 + seg * 8];
        *(bf16x8*)(D + (size_t)(row0 + row) * M_ + seg * 8) = v;
    }
}

// ---- K3: fused probes + evidence + sim + masked max + sum -> logits ------
// Grid dim3(B_, 4): 128 probes/block, 2 probe-tiles per wave -> each D
// ds_read_b128 feeds 2 MFMAs (k_sim was ds-throughput-bound).
__global__ __launch_bounds__(256) void k_sim(const float* __restrict__ lp,
                                             const float* __restrict__ sW,
                                             const float* __restrict__ oW,
                                             const float* __restrict__ dW,
                                             const int* __restrict__ st,
                                             const int* __restrict__ ot,
                                             const int* __restrict__ sf,
                                             const int* __restrict__ ctx,
                                             const int* __restrict__ btw,
                                             const __bf16* __restrict__ D,
                                             float* __restrict__ out) {
    __shared__ __align__(16) __bf16 Dl[2][128 * 128];   // 2 x 32 KB
    __shared__ float evl[L_];
    __shared__ int anyf;
    const int t = threadIdx.x;
    const int lane = t & 63, w = t >> 6;
    const int rlo = lane & 15, g = lane >> 4;
    const int b = blockIdx.x, pt = blockIdx.y;

    const __bf16* Db = D + (size_t)b * L_ * M_;

    // ---- issue chunk-0 DMA first (overlaps probe build) ----
#pragma unroll
    for (int q = 0; q < 8; ++q)
        GLL16(Db + q * 2048 + w * 512 + lane * 8, &Dl[0][q * 2048 + w * 512]);

    // ---- evidence (fused) ----
    if (t == 0) anyf = 0;
    __syncthreads();
    int v0 = btw[b * L_ + t], v1 = btw[b * L_ + t + 256];
    int c0 = ctx[b * L_ + t], c1 = ctx[b * L_ + t + 256];
    if (v0 | v1) anyf = 1;          // benign race: all writers store 1
    __syncthreads();
    const int any = anyf;
    evl[t]       = (any ? v0 : c0) ? 1.0f : 0.0f;
    evl[t + 256] = (any ? v1 : c1) ? 1.0f : 0.0f;

    // ---- probe build: 2 tiles per wave, in-register ----
    const int sb = st[b], ob = ot[b], db = sf[b];
    const float* sv = sW + sb * M_;
    const float* ov = oW + ob * M_;
    const float* dv = dW + db * M_;
    bf16x8 qF[2][4];
#pragma unroll
    for (int pt2 = 0; pt2 < 2; ++pt2) {
        const float* lpp = lp + (size_t)(pt * 128 + w * 32 + pt2 * 16 + rlo) * M_;
        float qv[32];
        float ssq = 0.f;
#pragma unroll
        for (int ks = 0; ks < 4; ++ks) {
#pragma unroll
            for (int h = 0; h < 2; ++h) {
                const int m0 = ks * 32 + g * 8 + h * 4;
                float4 a  = *(const float4*)(lpp + m0);
                float4 s4 = *(const float4*)(sv + m0);
                float4 o4 = *(const float4*)(ov + m0);
                float4 d4 = *(const float4*)(dv + m0);
                float x0 = a.x + s4.x + o4.x + d4.x;
                float x1 = a.y + s4.y + o4.y + d4.y;
                float x2 = a.z + s4.z + o4.z + d4.z;
                float x3 = a.w + s4.w + o4.w + d4.w;
                qv[ks * 8 + h * 4 + 0] = x0;
                qv[ks * 8 + h * 4 + 1] = x1;
                qv[ks * 8 + h * 4 + 2] = x2;
                qv[ks * 8 + h * 4 + 3] = x3;
                ssq += x0 * x0 + x1 * x1 + x2 * x2 + x3 * x3;
            }
        }
        ssq += __shfl_xor(ssq, 16);
        ssq += __shfl_xor(ssq, 32);
        const float scq = 1.0f / fmaxf(sqrtf(ssq), 1e-12f);
#pragma unroll
        for (int ks = 0; ks < 4; ++ks)
#pragma unroll
            for (int j = 0; j < 8; ++j)
                qF[pt2][ks][j] = (__bf16)(qv[ks * 8 + j] * scq);
    }

    __syncthreads();   // Dl[0] + evl ready

    // ---- MaxSim main loop: 1 barrier/chunk, DMA next while computing ----
    float vmax[2][4];
#pragma unroll
    for (int pt2 = 0; pt2 < 2; ++pt2)
#pragma unroll
        for (int r = 0; r < 4; ++r) vmax[pt2][r] = -1e30f;

    for (int tc = 0; tc < 4; ++tc) {
        const int cur = tc & 1;
        if (tc < 3) {
#pragma unroll
            for (int q = 0; q < 8; ++q)
                GLL16(Db + (tc + 1) * 16384 + q * 2048 + w * 512 + lane * 8,
                      &Dl[cur ^ 1][q * 2048 + w * 512]);
        }
#pragma unroll
        for (int tt = 0; tt < 8; ++tt) {
            f32x4 pacc[2] = {};
#pragma unroll
            for (int ks = 0; ks < 4; ++ks) {
                bf16x8 bF = *(const bf16x8*)&Dl[cur][swz4(tt * 16 + rlo, ks * 32 + g * 8)];
                pacc[0] = __builtin_amdgcn_mfma_f32_16x16x32_bf16(qF[0][ks], bF, pacc[0], 0, 0, 0);
                pacc[1] = __builtin_amdgcn_mfma_f32_16x16x32_bf16(qF[1][ks], bF, pacc[1], 0, 0, 0);
            }
            const float e = evl[tc * 128 + tt * 16 + rlo];
#pragma unroll
            for (int pt2 = 0; pt2 < 2; ++pt2)
#pragma unroll
                for (int r = 0; r < 4; ++r) {
                    float sv2 = (e > 0.5f) ? pacc[pt2][r] : -1e4f;
                    vmax[pt2][r] = fmaxf(vmax[pt2][r], sv2);
                }
        }
        __syncthreads();
    }

    // max over the 16 token-columns held across the 16-lane group
#pragma unroll
    for (int pt2 = 0; pt2 < 2; ++pt2)
#pragma unroll
        for (int r = 0; r < 4; ++r)
#pragma unroll
            for (int off = 1; off < 16; off <<= 1)
                vmax[pt2][r] = fmaxf(vmax[pt2][r], __shfl_xor(vmax[pt2][r], off));

#pragma unroll
    for (int pt2 = 0; pt2 < 2; ++pt2) {
        float psum = 0.f;
#pragma unroll
        for (int r = 0; r < 4; ++r)
            psum += (vmax[pt2][r] > -1000.0f) ? vmax[pt2][r] : 0.0f;
        float rtot = psum + __shfl_xor(psum, 16);
        if ((lane & 31) == 0) {
            int rr = pt * 16 + w * 4 + pt2 * 2 + (g >> 1);
            out[b * R_ + rr] = rtot;
        }
    }
}

// ---------------- launcher ----------------
extern "C" void kernel_launch(void* const* d_in, const int* in_sizes, int n_in,
                              void* d_out, int out_size, void* d_ws, size_t ws_size,
                              hipStream_t stream) {
    const float* hidden = (const float*)d_in[0];
    const int*   ctx    = (const int*)d_in[1];
    const int*   btw    = (const int*)d_in[2];
    const int*   st     = (const int*)d_in[3];
    const int*   ot     = (const int*)d_in[4];
    const int*   sf     = (const int*)d_in[5];
    const float* W      = (const float*)d_in[6];
    const float* lp     = (const float*)d_in[7];
    const float* sW     = (const float*)d_in[8];
    const float* oW     = (const float*)d_in[9];
    const float* dW     = (const float*)d_in[10];
    float* out = (float*)d_out;

    char* ws = (char*)d_ws;
    __bf16* Wt = (__bf16*)ws;                       // 196608 B (pre-swizzled)
    __bf16* D  = (__bf16*)(ws + 196608);            // 8 MB (pre-swizzled 4-bit)

    k_wt  <<<(HID_ * M_) / 256, 256, 0, stream>>>(W, Wt);
    k_proj<<<dim3(B_, 8), 512, 0, stream>>>(hidden, Wt, D);
    k_sim <<<dim3(B_, 4), 256, 0, stream>>>(lp, sW, oW, dW, st, ot, sf, ctx, btw, D, out);
}